// Round 13
// baseline (764.912 us; speedup 1.0000x reference)
//
#include <hip/hip_runtime.h>
#include <cmath>

static constexpr int Bb = 4, Ss = 1024, Ee = 768, Hh = 8, HDd = 96;
static constexpr int BS = Bb * Ss;                    // 4096 rows
static constexpr size_t SLOT_EF = (size_t)BS * Ee;    // elems of a [4096,768] slab

typedef __attribute__((ext_vector_type(8))) short short8v;
typedef __attribute__((ext_vector_type(4))) float f32x4;

__device__ __forceinline__ ushort f2b(float f) {
    unsigned u = __float_as_uint(f);
    return (ushort)((u + 0x7FFFu + ((u >> 16) & 1u)) >> 16);
}
__device__ __forceinline__ float b2f(ushort b) {
    return __uint_as_float(((unsigned)b) << 16);
}
__device__ __forceinline__ void gload16(const void* g, void* l) {
    __builtin_amdgcn_global_load_lds(
        (const __attribute__((address_space(1))) unsigned int*)g,
        (__attribute__((address_space(3))) unsigned int*)l, 16, 0, 0);
}

// ---------------- fp32 -> bf16 convert ----------------
__global__ __launch_bounds__(256) void cvt_bf16_k(
    const float* __restrict__ in, ushort* __restrict__ out, int n)
{
    const int i = (blockIdx.x * 256 + threadIdx.x) * 4;
    if (i >= n) return;
    const float4 v = *reinterpret_cast<const float4*>(in + i);
    ushort4 o;
    o.x = f2b(v.x); o.y = f2b(v.y); o.z = f2b(v.z); o.w = f2b(v.w);
    *reinterpret_cast<ushort4*>(out + i) = o;
}

// ---------------- batched W[K,N] fp32 -> Wt[N,K] bf16 transpose-convert ----------------
struct TDesc { const float* src; ushort* dst; int K; int N; int tile0; };
struct TPack { TDesc e[10]; };

__global__ __launch_bounds__(256) void tcvt_multi_k(TPack p)
{
    __shared__ float tile[64][65];
    const int tb = blockIdx.x;
    int idx = 0;
#pragma unroll
    for (int i = 1; i < 10; ++i) if (tb >= p.e[i].tile0) idx = i;
    const TDesc d = p.e[idx];
    const int lt = tb - d.tile0;
    const int ntn = d.N >> 6;
    const int nb = (lt % ntn) << 6;
    const int kb = (lt / ntn) << 6;
    const int t = threadIdx.x;
    {
        const int nn = t & 63, k4 = t >> 6;
#pragma unroll
        for (int r = 0; r < 16; ++r) {
            const int kk = (k4 << 4) + r;
            tile[kk][nn] = d.src[(size_t)(kb + kk) * d.N + nb + nn];
        }
    }
    __syncthreads();
    {
        const int kk = t & 63, n4 = t >> 6;
#pragma unroll
        for (int r = 0; r < 16; ++r) {
            const int nn = (n4 << 4) + r;
            d.dst[(size_t)(nb + nn) * d.K + kb + kk] = f2b(tile[kk][nn]);
        }
    }
}

// ---------------- concat 3 x 768 f32 biases ----------------
__global__ __launch_bounds__(256) void concat_bias_k(
    const float* __restrict__ a, const float* __restrict__ b,
    const float* __restrict__ c, float* __restrict__ o)
{
    const int i = blockIdx.x * 256 + threadIdx.x;
    if (i < 768) o[i] = a[i];
    else if (i < 1536) o[i] = b[i - 768];
    else if (i < 2304) o[i] = c[i - 1536];
}

// ---------------- bf16 MFMA GEMM (128x128 tile, BK=32, m97 structure) ----------------
template <int RELU, int WF32, int WB16>
__global__ __launch_bounds__(256) void gemm_bf16_k(
    const ushort* __restrict__ A, const ushort* __restrict__ Bt,
    const float* __restrict__ bias,
    float* __restrict__ Cf, ushort* __restrict__ Cb,
    int M, int N, int K)
{
    __shared__ ushort As[128 * 32];
    __shared__ ushort Bs[128 * 32];
    const int t = threadIdx.x, lane = t & 63, wid = t >> 6;
    const int bm = blockIdx.y, bn = blockIdx.x;
    const int wr = wid >> 1, wc = wid & 1;

    const int r0 = wid * 32 + (lane >> 2);
    const int sc = (lane & 3) * 8;
    const ushort* Ag0 = A  + (size_t)(bm * 128 + r0) * K + sc;
    const ushort* Ag1 = Ag0 + (size_t)16 * K;
    const ushort* Bg0 = Bt + (size_t)(bn * 128 + r0) * K + sc;
    const ushort* Bg1 = Bg0 + (size_t)16 * K;
    char* AsB = (char*)As + wid * 2048;
    char* BsB = (char*)Bs + wid * 2048;

    f32x4 acc[4][4];
#pragma unroll
    for (int m = 0; m < 4; ++m)
#pragma unroll
        for (int n = 0; n < 4; ++n) acc[m][n] = (f32x4){0.f, 0.f, 0.f, 0.f};

    const int fr = lane & 15, ks = (lane >> 4) * 8;

    for (int k0 = 0; k0 < K; k0 += 32) {
        __syncthreads();
        gload16(Ag0 + k0, AsB);
        gload16(Ag1 + k0, AsB + 1024);
        gload16(Bg0 + k0, BsB);
        gload16(Bg1 + k0, BsB + 1024);
        __syncthreads();

        short8v a[4], b[4];
#pragma unroll
        for (int m = 0; m < 4; ++m)
            a[m] = *reinterpret_cast<const short8v*>(&As[(wr * 64 + m * 16 + fr) * 32 + ks]);
#pragma unroll
        for (int n = 0; n < 4; ++n)
            b[n] = *reinterpret_cast<const short8v*>(&Bs[(wc * 64 + n * 16 + fr) * 32 + ks]);
#pragma unroll
        for (int m = 0; m < 4; ++m)
#pragma unroll
            for (int n = 0; n < 4; ++n)
                acc[m][n] = __builtin_amdgcn_mfma_f32_16x16x32_bf16(a[m], b[n], acc[m][n], 0, 0, 0);
    }

    const int col0 = bn * 128 + wc * 64 + (lane & 15);
    const int rw0  = bm * 128 + wr * 64 + (lane >> 4) * 4;
#pragma unroll
    for (int n = 0; n < 4; ++n) {
        const int col = col0 + n * 16;
        const float bv = bias[col];
#pragma unroll
        for (int m = 0; m < 4; ++m) {
            const f32x4 v = acc[m][n];
#pragma unroll
            for (int r = 0; r < 4; ++r) {
                const int row = rw0 + m * 16 + r;
                float val = v[r] + bv;
                if (RELU) val = fmaxf(val, 0.f);
                if (WF32) Cf[(size_t)row * N + col] = val;
                if (WB16) Cb[(size_t)row * N + col] = f2b(val);
            }
        }
    }
}

// ---------------- batch-axis attention: one wave per (s,h) ----------------
__global__ __launch_bounds__(256) void attn_wave_k(
    const ushort* __restrict__ qkv, ushort* __restrict__ ao)
{
    const int wv = (blockIdx.x << 2) + (threadIdx.x >> 6);  // 0..8191
    const int lane = threadIdx.x & 63;
    const int s = wv >> 3, h = wv & 7;
    const int c0 = h * HDd;
    const bool has2 = lane < 32;

    float qq[4][2], kk[4][2];
#pragma unroll
    for (int b = 0; b < 4; ++b) {
        const size_t base = (size_t)(b * Ss + s) * 2304 + c0;
        qq[b][0] = b2f(qkv[base + lane]);
        qq[b][1] = has2 ? b2f(qkv[base + 64 + lane]) : 0.f;
        kk[b][0] = b2f(qkv[base + 768 + lane]);
        kk[b][1] = has2 ? b2f(qkv[base + 768 + 64 + lane]) : 0.f;
    }
    float sc[4][4];
#pragma unroll
    for (int b = 0; b < 4; ++b)
#pragma unroll
        for (int c = 0; c < 4; ++c)
            sc[b][c] = qq[b][0] * kk[c][0] + qq[b][1] * kk[c][1];
#pragma unroll
    for (int msk = 1; msk < 64; msk <<= 1)
#pragma unroll
        for (int b = 0; b < 4; ++b)
#pragma unroll
            for (int c = 0; c < 4; ++c)
                sc[b][c] += __shfl_xor(sc[b][c], msk, 64);

    const float scale = 0.10206207261596577f;  // 1/sqrt(96)
    float at[4][4];
#pragma unroll
    for (int b = 0; b < 4; ++b) {
        const float mx = fmaxf(fmaxf(sc[b][0], sc[b][1]), fmaxf(sc[b][2], sc[b][3]));
        float sum = 0.f;
#pragma unroll
        for (int c = 0; c < 4; ++c) { at[b][c] = expf((sc[b][c] - mx) * scale); sum += at[b][c]; }
        const float inv = 1.f / sum;
#pragma unroll
        for (int c = 0; c < 4; ++c) at[b][c] *= inv;
    }

    float vv[4][2];
#pragma unroll
    for (int c = 0; c < 4; ++c) {
        const size_t base = (size_t)(c * Ss + s) * 2304 + 1536 + c0;
        vv[c][0] = b2f(qkv[base + lane]);
        vv[c][1] = has2 ? b2f(qkv[base + 64 + lane]) : 0.f;
    }
#pragma unroll
    for (int b = 0; b < 4; ++b) {
        float o0 = 0.f, o1 = 0.f;
#pragma unroll
        for (int c = 0; c < 4; ++c) { o0 = fmaf(at[b][c], vv[c][0], o0); o1 = fmaf(at[b][c], vv[c][1], o1); }
        const size_t obase = (size_t)(b * Ss + s) * Ee + c0;
        ao[obase + lane] = f2b(o0);
        if (has2) ao[obase + 64 + lane] = f2b(o1);
    }
}

// ---------------- probs = m1[BS,384] @ w2[384,1] + b2 ----------------
__global__ __launch_bounds__(256) void mlp2_probs_k(
    const float* __restrict__ m1, const float* __restrict__ w2,
    const float* __restrict__ b2, float* __restrict__ probs)
{
    const int gid = blockIdx.x * 256 + threadIdx.x;
    const int row = gid >> 6, lane = gid & 63;
    if (row >= BS) return;
    float acc = 0.f;
    for (int kk = lane; kk < 384; kk += 64)
        acc = fmaf(m1[(size_t)row * 384 + kk], w2[kk], acc);
#pragma unroll
    for (int off = 32; off > 0; off >>= 1) acc += __shfl_down(acc, off, 64);
    if (lane == 0) probs[row] = acc + b2[0];
}

// ---------------- ba = r1[BS,384] @ w2[384,3] + b2 ----------------
__global__ __launch_bounds__(256) void rb2_ba_k(
    const float* __restrict__ r1, const float* __restrict__ w2,
    const float* __restrict__ b2, float* __restrict__ ba)
{
    const int gid = blockIdx.x * 256 + threadIdx.x;
    const int row = gid >> 6, lane = gid & 63;
    if (row >= BS) return;
    float a0 = 0.f, a1 = 0.f, a2 = 0.f;
    for (int kk = lane; kk < 384; kk += 64) {
        const float r = r1[(size_t)row * 384 + kk];
        a0 = fmaf(r, w2[kk * 3 + 0], a0);
        a1 = fmaf(r, w2[kk * 3 + 1], a1);
        a2 = fmaf(r, w2[kk * 3 + 2], a2);
    }
#pragma unroll
    for (int off = 32; off > 0; off >>= 1) {
        a0 += __shfl_down(a0, off, 64);
        a1 += __shfl_down(a1, off, 64);
        a2 += __shfl_down(a2, off, 64);
    }
    if (lane == 0) {
        ba[(size_t)row * 3 + 0] = a0 + b2[0];
        ba[(size_t)row * 3 + 1] = a1 + b2[1];
        ba[(size_t)row * 3 + 2] = a2 + b2[2];
    }
}

// ---------------- contacts fill ----------------
__global__ __launch_bounds__(256) void contacts_k(
    const float* __restrict__ probs, float* __restrict__ out)
{
    const int f4 = blockIdx.x * 256 + threadIdx.x;
    if (f4 >= (Bb * Ss * Ss) / 4) return;
    const int row = f4 >> 8;
    const float p = probs[row];
    reinterpret_cast<float4*>(out)[f4] = make_float4(p, p, p, p);
}

// ---------------- steps + cumsum, padded float4 output ----------------
__global__ __launch_bounds__(1024) void steps_cumsum_k(
    const float* __restrict__ ba, float* __restrict__ sPad)
{
    const int b = blockIdx.x;
    const int i = threadIdx.x;
    const int row = b * Ss + i;
    const float phi = ba[(size_t)row * 3 + 0];
    const float psi = ba[(size_t)row * 3 + 1];
    const float cpsi = cosf(psi);
    float x = 3.8f * cosf(phi) * cpsi;
    float y = 3.8f * sinf(phi) * cpsi;
    float z = 3.8f * sinf(psi);
    if (i == 0) { x = 0.f; y = 0.f; z = 0.f; }
    __shared__ float sx[1024], sy[1024], sz[1024];
    sx[i] = x; sy[i] = y; sz[i] = z;
    for (int off = 1; off < 1024; off <<= 1) {
        __syncthreads();
        float ax = 0.f, ay = 0.f, az = 0.f;
        if (i >= off) { ax = sx[i - off]; ay = sy[i - off]; az = sz[i - off]; }
        __syncthreads();
        sx[i] += ax; sy[i] += ay; sz[i] += az;
    }
    *reinterpret_cast<float4*>(sPad + ((size_t)row << 2)) = make_float4(sx[i], sy[i], sz[i], 0.f);
}

// ---------------- 50 Adam steps, dataflow-pipelined (no global barrier) ----------------
// 256 blocks x 512 thr, cooperative (residency). Block bk: batch=bk>>6, source-block
// sb=bk&63 owns 16 rows (2/wave, positions live in registers across steps).
// Per step: consume 16 granules (64 rows each) of the batch as their producers' flags
// appear (64-lane poll + ballot), loading ready granules to LDS and accumulating
// immediately — wait only for stragglers. Writes agent-scope; per-step flag slots;
// 3-buffer rotation (skew<=1 concurrent step proven => no WAR race).
__global__ __launch_bounds__(512) void adam_pipe_k(
    const float* __restrict__ sInit, float* __restrict__ b0f, float* __restrict__ b1f,
    float* __restrict__ b2f, float* __restrict__ outS,
    const float* __restrict__ probs, unsigned* flags)
{
    const int tid = threadIdx.x, lane = tid & 63, wv = tid >> 6;  // wv 0..7
    const int bk = blockIdx.x;           // 0..255
    const int batch = bk >> 6;
    const int sb = bk & 63;
    const int jbase = batch << 10;
    const int lr = sb * 16 + wv * 2;     // own 2 rows (offset within batch)
    const int rbase = jbase + lr;

    __shared__ float sx[1024], sy[1024], sz[1024], pSh[1024];
    __shared__ unsigned gmaskSh;
    for (int i = tid; i < 1024; i += 512) pSh[i] = probs[jbase + i];

    // own state in registers
    float srx[2], sry[2], srz[2], pr[2];
#pragma unroll
    for (int r = 0; r < 2; ++r) {
        const float4 q = *reinterpret_cast<const float4*>(sInit + (((size_t)(rbase + r)) << 2));
        srx[r] = q.x; sry[r] = q.y; srz[r] = q.z;
        pr[r] = probs[rbase + r];
    }
    float m[2][3] = {}, v[2][3] = {};
    float pb1 = 1.f, pb2 = 1.f;
    const float invN = 1.f / 4194304.f;  // B*S*S
    float* bufs[3] = { b0f, b1f, b2f };

    for (int t = 1; t <= 50; ++t) {
        const float* rbuf = (t == 1) ? sInit : bufs[(t - 1) % 3];
        float* wbuf = bufs[t % 3];
        const unsigned* flgIn = flags + (((t - 2) * 4 + batch) << 6);  // valid t>=2

        pb1 *= 0.9f; pb2 *= 0.999f;
        const float bc1 = 1.f / (1.f - pb1);
        const float bc2 = 1.f / (1.f - pb2);

        unsigned done = 0;
        float g[2][3] = {};
        while (done != 0xFFFFu) {
            if (wv == 0) {
                unsigned gm = 0xFFFFu;
                if (t > 1) {
                    const unsigned f = __hip_atomic_load(flgIn + lane, __ATOMIC_RELAXED,
                                                         __HIP_MEMORY_SCOPE_AGENT);
                    const unsigned long long rdy = __ballot(f != 0u);
                    gm = 0;
#pragma unroll
                    for (int k = 0; k < 16; ++k)
                        if (((rdy >> (4 * k)) & 0xFull) == 0xFull) gm |= (1u << k);
                }
                if (lane == 0) gmaskSh = gm;
            }
            __syncthreads();
            const unsigned newg = gmaskSh & ~done;
            if (newg) {
                // designated waves load new granules into LDS (LLC-direct loads)
#pragma unroll 1
                for (int gi = 0; gi < 16; ++gi) {
                    if (((newg >> gi) & 1u) && ((gi & 7) == wv)) {
                        const int j = (gi << 6) + lane;
                        const float* p = rbuf + (((size_t)(jbase + j)) << 2);
                        const unsigned long long xy = __hip_atomic_load(
                            (const unsigned long long*)p, __ATOMIC_RELAXED,
                            __HIP_MEMORY_SCOPE_AGENT);
                        const float zz = __hip_atomic_load(p + 2, __ATOMIC_RELAXED,
                                                           __HIP_MEMORY_SCOPE_AGENT);
                        sx[j] = __uint_as_float((unsigned)xy);
                        sy[j] = __uint_as_float((unsigned)(xy >> 32));
                        sz[j] = zz;
                    }
                }
            }
            __syncthreads();
            if (newg) {
#pragma unroll 1
                for (int gi = 0; gi < 16; ++gi) {
                    if ((newg >> gi) & 1u) {
                        const int j = (gi << 6) + lane;
                        const float qx = sx[j], qy = sy[j], qz = sz[j];
                        const float pj = pSh[j];
#pragma unroll
                        for (int r = 0; r < 2; ++r) {
                            const float dx = srx[r] - qx, dy = sry[r] - qy, dz = srz[r] - qz;
                            const float d2 = dx * dx + dy * dy + dz * dz;
                            if (d2 > 0.f) {
                                const float w = ((d2 > 64.f) ? 1.f : -1.f) * (pr[r] + pj) * rsqrtf(d2);
                                g[r][0] = fmaf(w, dx, g[r][0]);
                                g[r][1] = fmaf(w, dy, g[r][1]);
                                g[r][2] = fmaf(w, dz, g[r][2]);
                            }
                        }
                    }
                }
                done |= newg;
            } else {
                __builtin_amdgcn_s_sleep(1);
            }
        }

        // reduce across lanes; replicated Adam update keeps own rows in registers
#pragma unroll
        for (int msk = 1; msk < 64; msk <<= 1)
#pragma unroll
            for (int r = 0; r < 2; ++r)
#pragma unroll
                for (int c = 0; c < 3; ++c)
                    g[r][c] += __shfl_xor(g[r][c], msk, 64);

#pragma unroll
        for (int r = 0; r < 2; ++r) {
            float ns[3];
            const float sc_[3] = { srx[r], sry[r], srz[r] };
#pragma unroll
            for (int c = 0; c < 3; ++c) {
                const float gg = g[r][c] * invN;
                m[r][c] = 0.9f * m[r][c] + 0.1f * gg;
                v[r][c] = 0.999f * v[r][c] + 0.001f * gg * gg;
                ns[c] = sc_[c] - 0.01f * (m[r][c] * bc1) / (sqrtf(v[r][c] * bc2) + 1e-8f);
            }
            srx[r] = ns[0]; sry[r] = ns[1]; srz[r] = ns[2];
        }

        if (t == 50) {
            if (lane == 0) {
#pragma unroll
                for (int r = 0; r < 2; ++r) {
                    outS[(size_t)(rbase + r) * 3 + 0] = srx[r];
                    outS[(size_t)(rbase + r) * 3 + 1] = sry[r];
                    outS[(size_t)(rbase + r) * 3 + 2] = srz[r];
                }
            }
            return;
        }

        if (lane == 0) {
#pragma unroll
            for (int r = 0; r < 2; ++r) {
                float* dst = wbuf + (((size_t)(rbase + r)) << 2);
                const unsigned long long xy =
                    ((unsigned long long)__float_as_uint(sry[r]) << 32)
                    | (unsigned long long)__float_as_uint(srx[r]);
                __hip_atomic_store((unsigned long long*)dst, xy,
                                   __ATOMIC_RELAXED, __HIP_MEMORY_SCOPE_AGENT);
                __hip_atomic_store(dst + 2, srz[r],
                                   __ATOMIC_RELAXED, __HIP_MEMORY_SCOPE_AGENT);
            }
        }
        __syncthreads();  // all 16 rows' stores drained (vmcnt) before flag
        if (tid == 0)
            __hip_atomic_store(flags + (((t - 1) * 4 + batch) << 6) + sb, 1u,
                               __ATOMIC_RELEASE, __HIP_MEMORY_SCOPE_AGENT);
        // no further sync: next step's LDS writes are fenced by the loop's two
        // syncthreads before any wave touches sx/sy/sz again
    }
}

extern "C" void kernel_launch(void* const* d_in, const int* in_sizes, int n_in,
                              void* d_out, int out_size, void* d_ws, size_t ws_size,
                              hipStream_t stream)
{
    const float* x     = (const float*)d_in[0];
    const float* bb_w1 = (const float*)d_in[1];
    const float* bb_b1 = (const float*)d_in[2];
    const float* bb_w2 = (const float*)d_in[3];
    const float* bb_b2 = (const float*)d_in[4];
    const float* sc_w1 = (const float*)d_in[5];
    const float* sc_b1 = (const float*)d_in[6];
    const float* sc_w2 = (const float*)d_in[7];
    const float* sc_b2 = (const float*)d_in[8];
    const float* wq_p = (const float*)d_in[9];  const float* bq = (const float*)d_in[10];
    const float* wk_p = (const float*)d_in[11]; const float* bk = (const float*)d_in[12];
    const float* wv_p = (const float*)d_in[13]; const float* bv = (const float*)d_in[14];
    const float* wo_p = (const float*)d_in[15]; const float* bo = (const float*)d_in[16];
    const float* mlp_w1 = (const float*)d_in[17]; const float* mlp_b1 = (const float*)d_in[18];
    const float* mlp_w2 = (const float*)d_in[19]; const float* mlp_b2 = (const float*)d_in[20];
    const float* rb_w1 = (const float*)d_in[21]; const float* rb_b1 = (const float*)d_in[22];
    const float* rb_w2 = (const float*)d_in[23]; const float* rb_b2 = (const float*)d_in[24];
    // rs_* dead in reference.

    float* out_backbone = (float*)d_out;
    float* out_side     = out_backbone + SLOT_EF;
    float* out_contacts = out_side + SLOT_EF;
    float* out_struct   = out_contacts + (size_t)Bb * Ss * Ss;

    // ---- workspace ----
    ushort* cur = (ushort*)d_ws;
    ushort* xb        = cur; cur += SLOT_EF;
    ushort* mb        = cur; cur += SLOT_EF;
    ushort* backboneb = cur; cur += SLOT_EF;
    ushort* s1b       = cur; cur += (size_t)BS * 384;
    ushort* bb_w1t    = cur; cur += 768 * 768;
    ushort* bb_w2t    = cur; cur += 768 * 768;
    ushort* qkvWt     = cur; cur += 2304 * 768;
    ushort* wot       = cur; cur += 768 * 768;
    ushort* sc_w1t    = cur; cur += 768 * 384;
    ushort* sc_w2t    = cur; cur += 768 * 384;
    ushort* mlp_w1t   = cur; cur += 768 * 384;
    ushort* rb_w1t    = cur; cur += 768 * 384;
    float* fcur = (float*)cur;
    float* qkvBias = fcur; fcur += 2304;
    float* probs   = fcur; fcur += BS;
    float* ba      = fcur; fcur += 3 * BS;
    float* sPA     = fcur; fcur += 4 * BS;
    float* rb0     = fcur; fcur += 4 * BS;
    float* rb1     = fcur; fcur += 4 * BS;
    float* rb2     = fcur; fcur += 4 * BS;
    unsigned* flags = (unsigned*)fcur; fcur += 50 * 4 * 64;  // [step][batch][src]

    // d_out region aliases (dead until their final write):
    ushort* qkvb = (ushort*)out_backbone;
    ushort* aob  = (ushort*)out_contacts;
    ushort* h1b  = (ushort*)out_contacts;
    float*  m1f  = out_side + (size_t)BS * 384;
    float*  r1f  = (float*)xb;

    const dim3 blk(256);
    const dim3 gEE(768 / 128, BS / 128);
    const dim3 gEH(384 / 128, BS / 128);
    const dim3 gQKV(2304 / 128, BS / 128);

    // ---- converts ----
    cvt_bf16_k<<<dim3((int)(SLOT_EF / 4 / 256)), blk, 0, stream>>>(x, xb, (int)SLOT_EF);
    {
        TPack tp; int t0 = 0; int ti = 0;
        auto add = [&](const float* s, ushort* d, int K, int N) {
            tp.e[ti].src = s; tp.e[ti].dst = d; tp.e[ti].K = K; tp.e[ti].N = N; tp.e[ti].tile0 = t0;
            t0 += (N / 64) * (K / 64); ++ti;
        };
        add(bb_w1, bb_w1t, 768, 768);
        add(bb_w2, bb_w2t, 768, 768);
        add(wq_p, qkvWt,                 768, 768);
        add(wk_p, qkvWt + 768 * 768,     768, 768);
        add(wv_p, qkvWt + 2 * 768 * 768, 768, 768);
        add(wo_p, wot, 768, 768);
        add(sc_w1, sc_w1t, 768, 384);
        add(sc_w2, sc_w2t, 384, 768);
        add(mlp_w1, mlp_w1t, 768, 384);
        add(rb_w1, rb_w1t, 768, 384);
        tcvt_multi_k<<<dim3(t0), blk, 0, stream>>>(tp);
    }
    concat_bias_k<<<dim3(9), blk, 0, stream>>>(bq, bk, bv, qkvBias);

    // ---- contact predictor first (qkvb occupies backbone/side regions) ----
    gemm_bf16_k<0, 0, 1><<<gQKV, blk, 0, stream>>>(xb, qkvWt, qkvBias, nullptr, qkvb, BS, 2304, 768);
    attn_wave_k<<<dim3(Ss * Hh / 4), blk, 0, stream>>>(qkvb, aob);
    gemm_bf16_k<0, 0, 1><<<gEE, blk, 0, stream>>>(aob, wot, bo, nullptr, mb, BS, 768, 768);
    gemm_bf16_k<1, 1, 0><<<gEH, blk, 0, stream>>>(mb, mlp_w1t, mlp_b1, m1f, nullptr, BS, 384, 768);
    mlp2_probs_k<<<dim3(BS * 64 / 256), blk, 0, stream>>>(m1f, mlp_w2, mlp_b2, probs);

    // ---- backbone / side (qkvb dead now) ----
    gemm_bf16_k<1, 0, 1><<<gEE, blk, 0, stream>>>(xb, bb_w1t, bb_b1, nullptr, h1b, BS, 768, 768);
    gemm_bf16_k<0, 1, 1><<<gEE, blk, 0, stream>>>(h1b, bb_w2t, bb_b2, out_backbone, backboneb, BS, 768, 768);
    gemm_bf16_k<1, 0, 1><<<gEH, blk, 0, stream>>>(backboneb, sc_w1t, sc_b1, nullptr, s1b, BS, 384, 768);
    gemm_bf16_k<0, 1, 0><<<gEE, blk, 0, stream>>>(s1b, sc_w2t, sc_b2, out_side, nullptr, BS, 768, 384);

    // ---- contacts fill (h1b dead) ----
    contacts_k<<<dim3(Bb * Ss * Ss / 4 / 256), blk, 0, stream>>>(probs, out_contacts);

    // ---- structure refiner ----
    gemm_bf16_k<1, 1, 0><<<gEH, blk, 0, stream>>>(backboneb, rb_w1t, rb_b1, r1f, nullptr, BS, 384, 768);
    rb2_ba_k<<<dim3(BS * 64 / 256), blk, 0, stream>>>(r1f, rb_w2, rb_b2, ba);
    steps_cumsum_k<<<dim3(Bb), dim3(1024), 0, stream>>>(ba, sPA);

    // ---- Adam: one cooperative launch, dataflow-pipelined (no global barrier) ----
    hipMemsetAsync(flags, 0, (size_t)50 * 4 * 64 * sizeof(unsigned), stream);
    {
        void* args[] = { (void*)&sPA, (void*)&rb0, (void*)&rb1, (void*)&rb2,
                         (void*)&out_struct, (void*)&probs, (void*)&flags };
        hipLaunchCooperativeKernel(reinterpret_cast<void*>(adam_pipe_k),
                                   dim3(256), dim3(512), args, 0, stream);
    }
}

// Round 14
// 602.406 us; speedup vs baseline: 1.2698x; 1.2698x over previous
//
#include <hip/hip_runtime.h>
#include <cmath>

static constexpr int Bb = 4, Ss = 1024, Ee = 768, Hh = 8, HDd = 96;
static constexpr int BS = Bb * Ss;                    // 4096 rows
static constexpr size_t SLOT_EF = (size_t)BS * Ee;    // elems of a [4096,768] slab

typedef __attribute__((ext_vector_type(8))) short short8v;
typedef __attribute__((ext_vector_type(4))) float f32x4;

__device__ __forceinline__ ushort f2b(float f) {
    unsigned u = __float_as_uint(f);
    return (ushort)((u + 0x7FFFu + ((u >> 16) & 1u)) >> 16);
}
__device__ __forceinline__ float b2f(ushort b) {
    return __uint_as_float(((unsigned)b) << 16);
}
__device__ __forceinline__ void gload16(const void* g, void* l) {
    __builtin_amdgcn_global_load_lds(
        (const __attribute__((address_space(1))) unsigned int*)g,
        (__attribute__((address_space(3))) unsigned int*)l, 16, 0, 0);
}

// ---------------- fp32 -> bf16 convert ----------------
__global__ __launch_bounds__(256) void cvt_bf16_k(
    const float* __restrict__ in, ushort* __restrict__ out, int n)
{
    const int i = (blockIdx.x * 256 + threadIdx.x) * 4;
    if (i >= n) return;
    const float4 v = *reinterpret_cast<const float4*>(in + i);
    ushort4 o;
    o.x = f2b(v.x); o.y = f2b(v.y); o.z = f2b(v.z); o.w = f2b(v.w);
    *reinterpret_cast<ushort4*>(out + i) = o;
}

// ---------------- batched W[K,N] fp32 -> Wt[N,K] bf16 transpose-convert ----------------
struct TDesc { const float* src; ushort* dst; int K; int N; int tile0; };
struct TPack { TDesc e[10]; };

__global__ __launch_bounds__(256) void tcvt_multi_k(TPack p)
{
    __shared__ float tile[64][65];
    const int tb = blockIdx.x;
    int idx = 0;
#pragma unroll
    for (int i = 1; i < 10; ++i) if (tb >= p.e[i].tile0) idx = i;
    const TDesc d = p.e[idx];
    const int lt = tb - d.tile0;
    const int ntn = d.N >> 6;
    const int nb = (lt % ntn) << 6;
    const int kb = (lt / ntn) << 6;
    const int t = threadIdx.x;
    {
        const int nn = t & 63, k4 = t >> 6;
#pragma unroll
        for (int r = 0; r < 16; ++r) {
            const int kk = (k4 << 4) + r;
            tile[kk][nn] = d.src[(size_t)(kb + kk) * d.N + nb + nn];
        }
    }
    __syncthreads();
    {
        const int kk = t & 63, n4 = t >> 6;
#pragma unroll
        for (int r = 0; r < 16; ++r) {
            const int nn = (n4 << 4) + r;
            d.dst[(size_t)(nb + nn) * d.K + kb + kk] = f2b(tile[kk][nn]);
        }
    }
}

// ---------------- concat 3 x 768 f32 biases ----------------
__global__ __launch_bounds__(256) void concat_bias_k(
    const float* __restrict__ a, const float* __restrict__ b,
    const float* __restrict__ c, float* __restrict__ o)
{
    const int i = blockIdx.x * 256 + threadIdx.x;
    if (i < 768) o[i] = a[i];
    else if (i < 1536) o[i] = b[i - 768];
    else if (i < 2304) o[i] = c[i - 1536];
}

// ---------------- bf16 MFMA GEMM (128x128 tile, BK=32, m97 structure) ----------------
template <int RELU, int WF32, int WB16>
__global__ __launch_bounds__(256) void gemm_bf16_k(
    const ushort* __restrict__ A, const ushort* __restrict__ Bt,
    const float* __restrict__ bias,
    float* __restrict__ Cf, ushort* __restrict__ Cb,
    int M, int N, int K)
{
    __shared__ ushort As[128 * 32];
    __shared__ ushort Bs[128 * 32];
    const int t = threadIdx.x, lane = t & 63, wid = t >> 6;
    const int bm = blockIdx.y, bn = blockIdx.x;
    const int wr = wid >> 1, wc = wid & 1;

    const int r0 = wid * 32 + (lane >> 2);
    const int sc = (lane & 3) * 8;
    const ushort* Ag0 = A  + (size_t)(bm * 128 + r0) * K + sc;
    const ushort* Ag1 = Ag0 + (size_t)16 * K;
    const ushort* Bg0 = Bt + (size_t)(bn * 128 + r0) * K + sc;
    const ushort* Bg1 = Bg0 + (size_t)16 * K;
    char* AsB = (char*)As + wid * 2048;
    char* BsB = (char*)Bs + wid * 2048;

    f32x4 acc[4][4];
#pragma unroll
    for (int m = 0; m < 4; ++m)
#pragma unroll
        for (int n = 0; n < 4; ++n) acc[m][n] = (f32x4){0.f, 0.f, 0.f, 0.f};

    const int fr = lane & 15, ks = (lane >> 4) * 8;

    for (int k0 = 0; k0 < K; k0 += 32) {
        __syncthreads();
        gload16(Ag0 + k0, AsB);
        gload16(Ag1 + k0, AsB + 1024);
        gload16(Bg0 + k0, BsB);
        gload16(Bg1 + k0, BsB + 1024);
        __syncthreads();

        short8v a[4], b[4];
#pragma unroll
        for (int m = 0; m < 4; ++m)
            a[m] = *reinterpret_cast<const short8v*>(&As[(wr * 64 + m * 16 + fr) * 32 + ks]);
#pragma unroll
        for (int n = 0; n < 4; ++n)
            b[n] = *reinterpret_cast<const short8v*>(&Bs[(wc * 64 + n * 16 + fr) * 32 + ks]);
#pragma unroll
        for (int m = 0; m < 4; ++m)
#pragma unroll
            for (int n = 0; n < 4; ++n)
                acc[m][n] = __builtin_amdgcn_mfma_f32_16x16x32_bf16(a[m], b[n], acc[m][n], 0, 0, 0);
    }

    const int col0 = bn * 128 + wc * 64 + (lane & 15);
    const int rw0  = bm * 128 + wr * 64 + (lane >> 4) * 4;
#pragma unroll
    for (int n = 0; n < 4; ++n) {
        const int col = col0 + n * 16;
        const float bv = bias[col];
#pragma unroll
        for (int m = 0; m < 4; ++m) {
            const f32x4 v = acc[m][n];
#pragma unroll
            for (int r = 0; r < 4; ++r) {
                const int row = rw0 + m * 16 + r;
                float val = v[r] + bv;
                if (RELU) val = fmaxf(val, 0.f);
                if (WF32) Cf[(size_t)row * N + col] = val;
                if (WB16) Cb[(size_t)row * N + col] = f2b(val);
            }
        }
    }
}

// ---------------- batch-axis attention: one wave per (s,h) ----------------
__global__ __launch_bounds__(256) void attn_wave_k(
    const ushort* __restrict__ qkv, ushort* __restrict__ ao)
{
    const int wv = (blockIdx.x << 2) + (threadIdx.x >> 6);  // 0..8191
    const int lane = threadIdx.x & 63;
    const int s = wv >> 3, h = wv & 7;
    const int c0 = h * HDd;
    const bool has2 = lane < 32;

    float qq[4][2], kk[4][2];
#pragma unroll
    for (int b = 0; b < 4; ++b) {
        const size_t base = (size_t)(b * Ss + s) * 2304 + c0;
        qq[b][0] = b2f(qkv[base + lane]);
        qq[b][1] = has2 ? b2f(qkv[base + 64 + lane]) : 0.f;
        kk[b][0] = b2f(qkv[base + 768 + lane]);
        kk[b][1] = has2 ? b2f(qkv[base + 768 + 64 + lane]) : 0.f;
    }
    float sc[4][4];
#pragma unroll
    for (int b = 0; b < 4; ++b)
#pragma unroll
        for (int c = 0; c < 4; ++c)
            sc[b][c] = qq[b][0] * kk[c][0] + qq[b][1] * kk[c][1];
#pragma unroll
    for (int msk = 1; msk < 64; msk <<= 1)
#pragma unroll
        for (int b = 0; b < 4; ++b)
#pragma unroll
            for (int c = 0; c < 4; ++c)
                sc[b][c] += __shfl_xor(sc[b][c], msk, 64);

    const float scale = 0.10206207261596577f;  // 1/sqrt(96)
    float at[4][4];
#pragma unroll
    for (int b = 0; b < 4; ++b) {
        const float mx = fmaxf(fmaxf(sc[b][0], sc[b][1]), fmaxf(sc[b][2], sc[b][3]));
        float sum = 0.f;
#pragma unroll
        for (int c = 0; c < 4; ++c) { at[b][c] = expf((sc[b][c] - mx) * scale); sum += at[b][c]; }
        const float inv = 1.f / sum;
#pragma unroll
        for (int c = 0; c < 4; ++c) at[b][c] *= inv;
    }

    float vv[4][2];
#pragma unroll
    for (int c = 0; c < 4; ++c) {
        const size_t base = (size_t)(c * Ss + s) * 2304 + 1536 + c0;
        vv[c][0] = b2f(qkv[base + lane]);
        vv[c][1] = has2 ? b2f(qkv[base + 64 + lane]) : 0.f;
    }
#pragma unroll
    for (int b = 0; b < 4; ++b) {
        float o0 = 0.f, o1 = 0.f;
#pragma unroll
        for (int c = 0; c < 4; ++c) { o0 = fmaf(at[b][c], vv[c][0], o0); o1 = fmaf(at[b][c], vv[c][1], o1); }
        const size_t obase = (size_t)(b * Ss + s) * Ee + c0;
        ao[obase + lane] = f2b(o0);
        if (has2) ao[obase + 64 + lane] = f2b(o1);
    }
}

// ---------------- probs = m1[BS,384] @ w2[384,1] + b2 ----------------
__global__ __launch_bounds__(256) void mlp2_probs_k(
    const float* __restrict__ m1, const float* __restrict__ w2,
    const float* __restrict__ b2, float* __restrict__ probs)
{
    const int gid = blockIdx.x * 256 + threadIdx.x;
    const int row = gid >> 6, lane = gid & 63;
    if (row >= BS) return;
    float acc = 0.f;
    for (int kk = lane; kk < 384; kk += 64)
        acc = fmaf(m1[(size_t)row * 384 + kk], w2[kk], acc);
#pragma unroll
    for (int off = 32; off > 0; off >>= 1) acc += __shfl_down(acc, off, 64);
    if (lane == 0) probs[row] = acc + b2[0];
}

// ---------------- ba = r1[BS,384] @ w2[384,3] + b2 ----------------
__global__ __launch_bounds__(256) void rb2_ba_k(
    const float* __restrict__ r1, const float* __restrict__ w2,
    const float* __restrict__ b2, float* __restrict__ ba)
{
    const int gid = blockIdx.x * 256 + threadIdx.x;
    const int row = gid >> 6, lane = gid & 63;
    if (row >= BS) return;
    float a0 = 0.f, a1 = 0.f, a2 = 0.f;
    for (int kk = lane; kk < 384; kk += 64) {
        const float r = r1[(size_t)row * 384 + kk];
        a0 = fmaf(r, w2[kk * 3 + 0], a0);
        a1 = fmaf(r, w2[kk * 3 + 1], a1);
        a2 = fmaf(r, w2[kk * 3 + 2], a2);
    }
#pragma unroll
    for (int off = 32; off > 0; off >>= 1) {
        a0 += __shfl_down(a0, off, 64);
        a1 += __shfl_down(a1, off, 64);
        a2 += __shfl_down(a2, off, 64);
    }
    if (lane == 0) {
        ba[(size_t)row * 3 + 0] = a0 + b2[0];
        ba[(size_t)row * 3 + 1] = a1 + b2[1];
        ba[(size_t)row * 3 + 2] = a2 + b2[2];
    }
}

// ---------------- contacts fill ----------------
__global__ __launch_bounds__(256) void contacts_k(
    const float* __restrict__ probs, float* __restrict__ out)
{
    const int f4 = blockIdx.x * 256 + threadIdx.x;
    if (f4 >= (Bb * Ss * Ss) / 4) return;
    const int row = f4 >> 8;
    const float p = probs[row];
    reinterpret_cast<float4*>(out)[f4] = make_float4(p, p, p, p);
}

// ---------------- steps + cumsum; packs (x,y,z,probs) per row ----------------
__global__ __launch_bounds__(1024) void steps_cumsum_k(
    const float* __restrict__ ba, const float* __restrict__ probs,
    float* __restrict__ sPad)
{
    const int b = blockIdx.x;
    const int i = threadIdx.x;
    const int row = b * Ss + i;
    const float phi = ba[(size_t)row * 3 + 0];
    const float psi = ba[(size_t)row * 3 + 1];
    const float cpsi = cosf(psi);
    float x = 3.8f * cosf(phi) * cpsi;
    float y = 3.8f * sinf(phi) * cpsi;
    float z = 3.8f * sinf(psi);
    if (i == 0) { x = 0.f; y = 0.f; z = 0.f; }
    __shared__ float sx[1024], sy[1024], sz[1024];
    sx[i] = x; sy[i] = y; sz[i] = z;
    for (int off = 1; off < 1024; off <<= 1) {
        __syncthreads();
        float ax = 0.f, ay = 0.f, az = 0.f;
        if (i >= off) { ax = sx[i - off]; ay = sy[i - off]; az = sz[i - off]; }
        __syncthreads();
        sx[i] += ax; sy[i] += ay; sz[i] += az;
    }
    *reinterpret_cast<float4*>(sPad + ((size_t)row << 2)) =
        make_float4(sx[i], sy[i], sz[i], probs[row]);
}

// ---------------- one Adam step: plain kernel, kernel boundary = barrier ----------------
// 256 blocks x 512 thr. Block bk: batch = bk>>6, owns 16 rows, 2 rows/wave.
// All loads/stores are NORMAL cached ops (inter-kernel coherence via launch boundary).
// s ping-pong padded float4 carrying probs in .w; m,v in global as 2xfloat4 per row.
__global__ __launch_bounds__(512) void adam_step2_k(
    const float* __restrict__ sIn, float* __restrict__ sOut,
    float* __restrict__ mv, float* __restrict__ outS,
    float bc1, float bc2, int last)
{
    const int tid = threadIdx.x, lane = tid & 63, wv = tid >> 6;  // wv 0..7
    const int bk = blockIdx.x;          // 0..255
    const int batch = bk >> 6;
    const int jbase = batch << 10;
    const int lr = (bk & 63) * 16 + wv * 2;
    const int rbase = jbase + lr;

    __shared__ float sx[1024], sy[1024], sz[1024], pSh[1024];
    for (int r = tid; r < 1024; r += 512) {
        const float4 q = *reinterpret_cast<const float4*>(sIn + (((size_t)(jbase + r)) << 2));
        sx[r] = q.x; sy[r] = q.y; sz[r] = q.z; pSh[r] = q.w;
    }
    __syncthreads();

    const float invN = 1.f / 4194304.f;  // B*S*S
    float srx[2], sry[2], srz[2], pr[2], g[2][3] = {};
#pragma unroll
    for (int r = 0; r < 2; ++r) {
        srx[r] = sx[lr + r]; sry[r] = sy[lr + r]; srz[r] = sz[lr + r]; pr[r] = pSh[lr + r];
    }

    for (int it = 0; it < 16; ++it) {
        const int j = it * 64 + lane;
        const float qx = sx[j], qy = sy[j], qz = sz[j];
        const float pj = pSh[j];
#pragma unroll
        for (int r = 0; r < 2; ++r) {
            const float dx = srx[r] - qx, dy = sry[r] - qy, dz = srz[r] - qz;
            const float d2 = dx * dx + dy * dy + dz * dz;
            if (d2 > 0.f) {
                const float w = ((d2 > 64.f) ? 1.f : -1.f) * (pr[r] + pj) * rsqrtf(d2);
                g[r][0] = fmaf(w, dx, g[r][0]);
                g[r][1] = fmaf(w, dy, g[r][1]);
                g[r][2] = fmaf(w, dz, g[r][2]);
            }
        }
    }
#pragma unroll
    for (int msk = 1; msk < 64; msk <<= 1)
#pragma unroll
        for (int r = 0; r < 2; ++r)
#pragma unroll
            for (int c = 0; c < 3; ++c)
                g[r][c] += __shfl_xor(g[r][c], msk, 64);

    if (lane == 0) {
#pragma unroll
        for (int r = 0; r < 2; ++r) {
            const int row = rbase + r;
            float4 mva = *reinterpret_cast<const float4*>(mv + ((size_t)row << 3));      // m.x m.y m.z v.x
            float4 mvb = *reinterpret_cast<const float4*>(mv + ((size_t)row << 3) + 4);  // v.y v.z _ _
            float mArr[3] = { mva.x, mva.y, mva.z };
            float vArr[3] = { mva.w, mvb.x, mvb.y };
            const float sc_[3] = { srx[r], sry[r], srz[r] };
            float ns[3];
#pragma unroll
            for (int c = 0; c < 3; ++c) {
                const float gg = g[r][c] * invN;
                mArr[c] = 0.9f * mArr[c] + 0.1f * gg;
                vArr[c] = 0.999f * vArr[c] + 0.001f * gg * gg;
                ns[c] = sc_[c] - 0.01f * (mArr[c] * bc1) / (sqrtf(vArr[c] * bc2) + 1e-8f);
            }
            *reinterpret_cast<float4*>(mv + ((size_t)row << 3)) =
                make_float4(mArr[0], mArr[1], mArr[2], vArr[0]);
            *reinterpret_cast<float4*>(mv + ((size_t)row << 3) + 4) =
                make_float4(vArr[1], vArr[2], 0.f, 0.f);
            if (last) {
                outS[(size_t)row * 3 + 0] = ns[0];
                outS[(size_t)row * 3 + 1] = ns[1];
                outS[(size_t)row * 3 + 2] = ns[2];
            } else {
                *reinterpret_cast<float4*>(sOut + ((size_t)row << 2)) =
                    make_float4(ns[0], ns[1], ns[2], pr[r]);
            }
        }
    }
}

extern "C" void kernel_launch(void* const* d_in, const int* in_sizes, int n_in,
                              void* d_out, int out_size, void* d_ws, size_t ws_size,
                              hipStream_t stream)
{
    const float* x     = (const float*)d_in[0];
    const float* bb_w1 = (const float*)d_in[1];
    const float* bb_b1 = (const float*)d_in[2];
    const float* bb_w2 = (const float*)d_in[3];
    const float* bb_b2 = (const float*)d_in[4];
    const float* sc_w1 = (const float*)d_in[5];
    const float* sc_b1 = (const float*)d_in[6];
    const float* sc_w2 = (const float*)d_in[7];
    const float* sc_b2 = (const float*)d_in[8];
    const float* wq_p = (const float*)d_in[9];  const float* bq = (const float*)d_in[10];
    const float* wk_p = (const float*)d_in[11]; const float* bk = (const float*)d_in[12];
    const float* wv_p = (const float*)d_in[13]; const float* bv = (const float*)d_in[14];
    const float* wo_p = (const float*)d_in[15]; const float* bo = (const float*)d_in[16];
    const float* mlp_w1 = (const float*)d_in[17]; const float* mlp_b1 = (const float*)d_in[18];
    const float* mlp_w2 = (const float*)d_in[19]; const float* mlp_b2 = (const float*)d_in[20];
    const float* rb_w1 = (const float*)d_in[21]; const float* rb_b1 = (const float*)d_in[22];
    const float* rb_w2 = (const float*)d_in[23]; const float* rb_b2 = (const float*)d_in[24];
    // rs_* dead in reference.

    float* out_backbone = (float*)d_out;
    float* out_side     = out_backbone + SLOT_EF;
    float* out_contacts = out_side + SLOT_EF;
    float* out_struct   = out_contacts + (size_t)Bb * Ss * Ss;

    // ---- workspace ----
    ushort* cur = (ushort*)d_ws;
    ushort* xb        = cur; cur += SLOT_EF;
    ushort* mb        = cur; cur += SLOT_EF;
    ushort* backboneb = cur; cur += SLOT_EF;
    ushort* s1b       = cur; cur += (size_t)BS * 384;
    ushort* bb_w1t    = cur; cur += 768 * 768;
    ushort* bb_w2t    = cur; cur += 768 * 768;
    ushort* qkvWt     = cur; cur += 2304 * 768;
    ushort* wot       = cur; cur += 768 * 768;
    ushort* sc_w1t    = cur; cur += 768 * 384;
    ushort* sc_w2t    = cur; cur += 768 * 384;
    ushort* mlp_w1t   = cur; cur += 768 * 384;
    ushort* rb_w1t    = cur; cur += 768 * 384;
    float* fcur = (float*)cur;
    float* qkvBias = fcur; fcur += 2304;
    float* probs   = fcur; fcur += BS;
    float* ba      = fcur; fcur += 3 * BS;
    float* sPA     = fcur; fcur += 4 * BS;
    float* sPB     = fcur; fcur += 4 * BS;
    float* mvB     = fcur; fcur += 8 * BS;   // m(3)+v(3) padded to 8 per row

    // d_out region aliases (dead until their final write):
    ushort* qkvb = (ushort*)out_backbone;
    ushort* aob  = (ushort*)out_contacts;
    ushort* h1b  = (ushort*)out_contacts;
    float*  m1f  = out_side + (size_t)BS * 384;
    float*  r1f  = (float*)xb;

    const dim3 blk(256);
    const dim3 gEE(768 / 128, BS / 128);
    const dim3 gEH(384 / 128, BS / 128);
    const dim3 gQKV(2304 / 128, BS / 128);

    // ---- converts ----
    cvt_bf16_k<<<dim3((int)(SLOT_EF / 4 / 256)), blk, 0, stream>>>(x, xb, (int)SLOT_EF);
    {
        TPack tp; int t0 = 0; int ti = 0;
        auto add = [&](const float* s, ushort* d, int K, int N) {
            tp.e[ti].src = s; tp.e[ti].dst = d; tp.e[ti].K = K; tp.e[ti].N = N; tp.e[ti].tile0 = t0;
            t0 += (N / 64) * (K / 64); ++ti;
        };
        add(bb_w1, bb_w1t, 768, 768);
        add(bb_w2, bb_w2t, 768, 768);
        add(wq_p, qkvWt,                 768, 768);
        add(wk_p, qkvWt + 768 * 768,     768, 768);
        add(wv_p, qkvWt + 2 * 768 * 768, 768, 768);
        add(wo_p, wot, 768, 768);
        add(sc_w1, sc_w1t, 768, 384);
        add(sc_w2, sc_w2t, 384, 768);
        add(mlp_w1, mlp_w1t, 768, 384);
        add(rb_w1, rb_w1t, 768, 384);
        tcvt_multi_k<<<dim3(t0), blk, 0, stream>>>(tp);
    }
    concat_bias_k<<<dim3(9), blk, 0, stream>>>(bq, bk, bv, qkvBias);

    // ---- contact predictor first (qkvb occupies backbone/side regions) ----
    gemm_bf16_k<0, 0, 1><<<gQKV, blk, 0, stream>>>(xb, qkvWt, qkvBias, nullptr, qkvb, BS, 2304, 768);
    attn_wave_k<<<dim3(Ss * Hh / 4), blk, 0, stream>>>(qkvb, aob);
    gemm_bf16_k<0, 0, 1><<<gEE, blk, 0, stream>>>(aob, wot, bo, nullptr, mb, BS, 768, 768);
    gemm_bf16_k<1, 1, 0><<<gEH, blk, 0, stream>>>(mb, mlp_w1t, mlp_b1, m1f, nullptr, BS, 384, 768);
    mlp2_probs_k<<<dim3(BS * 64 / 256), blk, 0, stream>>>(m1f, mlp_w2, mlp_b2, probs);

    // ---- backbone / side (qkvb dead now) ----
    gemm_bf16_k<1, 0, 1><<<gEE, blk, 0, stream>>>(xb, bb_w1t, bb_b1, nullptr, h1b, BS, 768, 768);
    gemm_bf16_k<0, 1, 1><<<gEE, blk, 0, stream>>>(h1b, bb_w2t, bb_b2, out_backbone, backboneb, BS, 768, 768);
    gemm_bf16_k<1, 0, 1><<<gEH, blk, 0, stream>>>(backboneb, sc_w1t, sc_b1, nullptr, s1b, BS, 384, 768);
    gemm_bf16_k<0, 1, 0><<<gEE, blk, 0, stream>>>(s1b, sc_w2t, sc_b2, out_side, nullptr, BS, 768, 384);

    // ---- contacts fill (h1b dead) ----
    contacts_k<<<dim3(Bb * Ss * Ss / 4 / 256), blk, 0, stream>>>(probs, out_contacts);

    // ---- structure refiner ----
    gemm_bf16_k<1, 1, 0><<<gEH, blk, 0, stream>>>(backboneb, rb_w1t, rb_b1, r1f, nullptr, BS, 384, 768);
    rb2_ba_k<<<dim3(BS * 64 / 256), blk, 0, stream>>>(r1f, rb_w2, rb_b2, ba);
    steps_cumsum_k<<<dim3(Bb), dim3(1024), 0, stream>>>(ba, probs, sPA);

    // ---- Adam: 50 graph-launched step kernels (kernel boundary = barrier) ----
    hipMemsetAsync(mvB, 0, (size_t)8 * BS * sizeof(float), stream);
    for (int t = 1; t <= 50; ++t) {
        const float bc1 = (float)(1.0 / (1.0 - std::pow(0.9, (double)t)));
        const float bc2 = (float)(1.0 / (1.0 - std::pow(0.999, (double)t)));
        const float* sin_ = (t & 1) ? sPA : sPB;
        float* sout = (t & 1) ? sPB : sPA;
        adam_step2_k<<<dim3(256), dim3(512), 0, stream>>>(
            sin_, sout, mvB, out_struct, bc1, bc2, (t == 50) ? 1 : 0);
    }
}